// Round 10
// baseline (404.138 us; speedup 1.0000x reference)
//
#include <hip/hip_runtime.h>
#include <hip/hip_fp16.h>

// GATv2 x3 + FC on MI355X. N=50000, E=800000(+N self loops), F=128, H=4, C=32.
// R9: (a) gemm_mfma: 128-row tile, single LDS stage (A + both W, 102KB,
//     pad 136 -> 2-way banks), ONE barrier, operand-swapped MFMA so the
//     epilogue stores 4 consecutive out-cols per lane (8B stores, 4x fewer).
//     (b) fused_attn: 3-deep edge-row prefetch (gather-latency bound).
constexpr int FDIM = 128;   // H*C
constexpr float SLOPE = 0.2f;

using half8 = __attribute__((ext_vector_type(8))) _Float16;
using f32x4 = __attribute__((ext_vector_type(4))) float;
using h2v   = __attribute__((ext_vector_type(2))) _Float16;

union H2U { __half2 s; h2v v; unsigned int u; };

__device__ __forceinline__ float fdot2f(h2v a, h2v b, float c) {
  return __builtin_amdgcn_fdot2(a, b, c, false);
}

union U4 { uint4 u; __half2 h[4]; };

// logit partial for 8 features held as 4 half2: sum att*lrelu(xa+xr)
__device__ __forceinline__ float edge_logit(const __half2* xa2, const __half2* xr2,
                                            const h2v* att2, h2v c02) {
  float p = 0.f;
#pragma unroll
  for (int j = 0; j < 4; ++j) {
    H2U ua, ur;
    ua.s = xa2[j]; ur.s = xr2[j];
    h2v z = ua.v + ur.v;                              // v_pk_add_f16
    h2v lr = __builtin_elementwise_max(z, z * c02);   // lrelu = max(x, 0.2x)
    p = fdot2f(lr, att2[j], p);
  }
  return p;
}

// ---- prep_w: W[k][c] fp32 -> Wt[c][k] fp16, 6 matrices (one per block) ---
__global__ __launch_bounds__(256) void prep_w(
    const float* __restrict__ W0, const float* __restrict__ W1,
    const float* __restrict__ W2, const float* __restrict__ W3,
    const float* __restrict__ W4, const float* __restrict__ W5,
    __half* __restrict__ Wt) {
  const float* Ws[6] = {W0, W1, W2, W3, W4, W5};
  const float* W = Ws[blockIdx.x];
  __half* o = Wt + (size_t)blockIdx.x * FDIM * FDIM;
  const int t = threadIdx.x;
  const int c4 = (t & 31) * 4;
#pragma unroll
  for (int rep = 0; rep < 16; ++rep) {
    int k = (t >> 5) + rep * 8;
    float4 v = *(const float4*)(W + (size_t)k * FDIM + c4);
    o[(size_t)(c4 + 0) * FDIM + k] = __float2half(v.x);
    o[(size_t)(c4 + 1) * FDIM + k] = __float2half(v.y);
    o[(size_t)(c4 + 2) * FDIM + k] = __float2half(v.z);
    o[(size_t)(c4 + 3) * FDIM + k] = __float2half(v.w);
  }
}

// ---- gemm_mfma: xl = hin@Wl, xr = hin@Wr (fp16 out, fp32 accumulate) ----
// 128-row tile, 512 threads = 8 waves (sel=wv>>2 picks xl/xr, rb=wv&3 picks
// 32-row block). Single stage of A + both Wt into LDS, one barrier,
// 64 MFMA/wave. Operand-swapped: mfma(Wfrag, xfrag) -> lane holds 4
// consecutive out-cols of one row -> 8B vector stores.
template <typename TIN>
__global__ __launch_bounds__(512) void gemm_mfma(
    const TIN* __restrict__ hin, const __half* __restrict__ Wlt,
    const __half* __restrict__ Wrt, __half* __restrict__ xl,
    __half* __restrict__ xr, int n) {
  __shared__ __half Ah[128][136];       // pad 136: 272B rows -> 2-way banks
  __shared__ __half Bs[2][128][136];    // Wt slabs (col-major [outcol][k])
  const int tid = threadIdx.x;
  const int row0 = blockIdx.x * 128;
  const int wv = tid >> 6;
  const int lane = tid & 63;
  const int sel = wv >> 2;       // 0: xl, 1: xr
  const int rb = wv & 3;         // 32-row block within tile
  const int l15 = lane & 15;
  const int l4 = lane >> 4;      // 0..3

  {  // stage A: thread t -> row t>>2, col quarter (t&3)*32 (32 halves)
    const int r = tid >> 2, q = (tid & 3) * 32;
    const int gr = row0 + r;
    if constexpr (sizeof(TIN) == 4) {
#pragma unroll
      for (int u = 0; u < 4; ++u) {
        float4 v0 = make_float4(0.f, 0.f, 0.f, 0.f), v1 = v0;
        if (gr < n) {
          v0 = *(const float4*)((const float*)hin + (size_t)gr * FDIM + q + u * 8);
          v1 = *(const float4*)((const float*)hin + (size_t)gr * FDIM + q + u * 8 + 4);
        }
        union { uint4 u4; __half h[8]; } pk;
        pk.h[0] = __float2half(v0.x); pk.h[1] = __float2half(v0.y);
        pk.h[2] = __float2half(v0.z); pk.h[3] = __float2half(v0.w);
        pk.h[4] = __float2half(v1.x); pk.h[5] = __float2half(v1.y);
        pk.h[6] = __float2half(v1.z); pk.h[7] = __float2half(v1.w);
        *(uint4*)&Ah[r][q + u * 8] = pk.u4;
      }
    } else {
#pragma unroll
      for (int u = 0; u < 4; ++u) {
        uint4 v = make_uint4(0u, 0u, 0u, 0u);
        if (gr < n)
          v = *(const uint4*)((const __half*)hin + (size_t)gr * FDIM + q + u * 8);
        *(uint4*)&Ah[r][q + u * 8] = v;
      }
    }
  }
  {  // stage B: slab t>>8 (Wl/Wr); idx=t&255 -> col idx>>1, k-half (idx&1)*64
    const int slab = tid >> 8;
    const int idx = tid & 255;
    const int c = idx >> 1;
    const int kb = (idx & 1) * 64;
    const __half* Wsrc = slab ? Wrt : Wlt;
#pragma unroll
    for (int u = 0; u < 8; ++u) {
      uint4 v = *(const uint4*)(Wsrc + (size_t)c * FDIM + kb + u * 8);
      *(uint4*)&Bs[slab][c][kb + u * 8] = v;
    }
  }
  __syncthreads();

  f32x4 acc[2][8];
#pragma unroll
  for (int i = 0; i < 2; ++i)
#pragma unroll
    for (int j = 0; j < 8; ++j) acc[i][j] = (f32x4){0.f, 0.f, 0.f, 0.f};

#pragma unroll
  for (int ks = 0; ks < 4; ++ks) {
    half8 a0 = *(const half8*)&Ah[rb * 32 + l15][ks * 32 + l4 * 8];
    half8 a1 = *(const half8*)&Ah[rb * 32 + 16 + l15][ks * 32 + l4 * 8];
#pragma unroll
    for (int nf = 0; nf < 8; ++nf) {
      half8 w = *(const half8*)&Bs[sel][nf * 16 + l15][ks * 32 + l4 * 8];
      // swapped operands: D rows = W cols (output cols), D cols = x rows
      acc[0][nf] = __builtin_amdgcn_mfma_f32_16x16x32_f16(w, a0, acc[0][nf], 0, 0, 0);
      acc[1][nf] = __builtin_amdgcn_mfma_f32_16x16x32_f16(w, a1, acc[1][nf], 0, 0, 0);
    }
  }

  // epilogue: lane holds rows rb*32+af*16+l15; out-cols nf*16 + l4*4 .. +3
  __half* out = sel ? xr : xl;
#pragma unroll
  for (int af = 0; af < 2; ++af) {
    const int row = row0 + rb * 32 + af * 16 + l15;
    if (row < n) {
#pragma unroll
      for (int nf = 0; nf < 8; ++nf) {
        union { uint2 u; __half2 h[2]; } pk;
        pk.h[0] = __floats2half2_rn(acc[af][nf][0], acc[af][nf][1]);
        pk.h[1] = __floats2half2_rn(acc[af][nf][2], acc[af][nf][3]);
        *(uint2*)(out + (size_t)row * FDIM + nf * 16 + l4 * 4) = pk.u;
      }
    }
  }
}

// ---------------- CSR build: histogram -> hierarchical scan -> scatter ---
__global__ __launch_bounds__(256) void hist_dst(const int* __restrict__ dstI,
                                                int* __restrict__ deg, int e_cnt) {
  int i = blockIdx.x * blockDim.x + threadIdx.x;
  int stride = gridDim.x * blockDim.x;
  for (; i < e_cnt; i += stride) atomicAdd(&deg[dstI[i]], 1);
}

__global__ __launch_bounds__(1024) void scan_local(
    const int* __restrict__ deg, int* __restrict__ rowptr,
    int* __restrict__ btot, int n) {
  __shared__ int lds[1024];
  const int t = threadIdx.x;
  const int i = blockIdx.x * 1024 + t;
  int v = (i < n) ? deg[i] : 0;
  lds[t] = v;
  __syncthreads();
  for (int off = 1; off < 1024; off <<= 1) {
    int u = (t >= off) ? lds[t - off] : 0;
    __syncthreads();
    lds[t] += u;
    __syncthreads();
  }
  if (i < n) rowptr[i] = lds[t] - v;  // exclusive within block
  if (t == 1023) btot[blockIdx.x] = lds[1023];
}

__global__ __launch_bounds__(1024) void scan_btot(int* __restrict__ btot, int nb) {
  __shared__ int lds[1024];
  const int t = threadIdx.x;
  int v = (t < nb) ? btot[t] : 0;
  lds[t] = v;
  __syncthreads();
  for (int off = 1; off < 1024; off <<= 1) {
    int u = (t >= off) ? lds[t - off] : 0;
    __syncthreads();
    lds[t] += u;
    __syncthreads();
  }
  if (t < nb) btot[t] = lds[t] - v;
}

__global__ __launch_bounds__(1024) void scan_add(
    int* __restrict__ rowptr, int* __restrict__ rowcur,
    const int* __restrict__ btot, int n, int e_cnt) {
  const int i = blockIdx.x * 1024 + threadIdx.x;
  if (i < n) {
    int v = rowptr[i] + btot[blockIdx.x];
    rowptr[i] = v;
    rowcur[i] = v;
  }
  if (i == 0) rowptr[n] = e_cnt;
}

__global__ __launch_bounds__(256) void scatter_csr(
    const int* __restrict__ srcI, const int* __restrict__ dstI,
    int* __restrict__ rowcur, int* __restrict__ csr, int e_cnt) {
  int i = blockIdx.x * blockDim.x + threadIdx.x;
  int stride = gridDim.x * blockDim.x;
  for (; i < e_cnt; i += stride) {
    int pos = atomicAdd(&rowcur[dstI[i]], 1);
    csr[pos] = srcI[i];
  }
}

// ------- fused per-node GATv2: 4 edges/wave, packed fp16, 3-deep prefetch -
// lane = g*16 + q; group g handles edges rs+4t+g; lane q covers features
// q*8..q*8+7 (head = q>>2). Self-loop seeds group 0's state.
template <int LAST>
__global__ __launch_bounds__(256) void fused_attn(
    const __half* __restrict__ xl, const __half* __restrict__ xr,
    const int* __restrict__ rowptr, const int* __restrict__ csr,
    const float* __restrict__ att, const float* __restrict__ bias,
    const float* __restrict__ Wf, const float* __restrict__ bf,
    void* __restrict__ outp, int n) {
  const int nid = (int)((blockIdx.x * (size_t)blockDim.x + threadIdx.x) >> 6);
  const int lane = threadIdx.x & 63;
  if (nid >= n) return;
  const int g = lane >> 4;
  const int q = lane & 15;
  const int f8 = q * 8;
  const h2v c02 = {(_Float16)SLOPE, (_Float16)SLOPE};
  const float4 aA = *(const float4*)(att + f8);
  const float4 aB = *(const float4*)(att + f8 + 4);
  h2v att2[4] = {{(_Float16)aA.x, (_Float16)aA.y}, {(_Float16)aA.z, (_Float16)aA.w},
                 {(_Float16)aB.x, (_Float16)aB.y}, {(_Float16)aB.z, (_Float16)aB.w}};
  U4 xru, xlu;
  xru.u = *(const uint4*)(xr + (size_t)nid * FDIM + f8);
  xlu.u = *(const uint4*)(xl + (size_t)nid * FDIM + f8);

  // self-edge logit
  float ps = edge_logit(xlu.h, xru.h, att2, c02);
  ps += __shfl_xor(ps, 1);
  ps += __shfl_xor(ps, 2);

  float m = (g == 0) ? ps : -1e30f;
  float s = (g == 0) ? 1.f : 0.f;
  float acc[8];
#pragma unroll
  for (int j = 0; j < 4; ++j) {
    float2 f = __half22float2(xlu.h[j]);
    acc[2 * j] = (g == 0) ? f.x : 0.f;
    acc[2 * j + 1] = (g == 0) ? f.y : 0.f;
  }

  const int rs = rowptr[nid], re = rowptr[nid + 1];
  const int j0 = rs + g;
  bool v0 = j0 < re, v1 = (j0 + 4) < re, v2 = (j0 + 8) < re;
  U4 cur, nx1, nx2;
  cur.u = make_uint4(0u, 0u, 0u, 0u);
  nx1.u = cur.u; nx2.u = cur.u;
  if (v0) cur.u = *(const uint4*)(xl + (size_t)csr[j0] * FDIM + f8);
  if (v1) nx1.u = *(const uint4*)(xl + (size_t)csr[j0 + 4] * FDIM + f8);
  if (v2) nx2.u = *(const uint4*)(xl + (size_t)csr[j0 + 8] * FDIM + f8);

  for (int t = rs; t < re; t += 4) {
    const int jn = t + 12 + g;
    const bool vn = jn < re;
    U4 nx3;
    nx3.u = make_uint4(0u, 0u, 0u, 0u);
    if (vn) nx3.u = *(const uint4*)(xl + (size_t)csr[jn] * FDIM + f8);

    float p = edge_logit(cur.h, xru.h, att2, c02);
    p += __shfl_xor(p, 1);
    p += __shfl_xor(p, 2);
    if (v0) {
      float mn = fmaxf(m, p);
      float sc = __expf(m - mn);
      float w = __expf(p - mn);
      s = fmaf(s, sc, w);
#pragma unroll
      for (int j = 0; j < 4; ++j) {  // fma_mix: (float)half fused by compiler
        acc[2 * j] = fmaf(acc[2 * j], sc, w * (float)__low2half(cur.h[j]));
        acc[2 * j + 1] = fmaf(acc[2 * j + 1], sc, w * (float)__high2half(cur.h[j]));
      }
      m = mn;
    }
    v0 = v1; v1 = v2; v2 = vn;
    cur = nx1; nx1 = nx2; nx2 = nx3;
  }

  // merge the 4 groups' online-softmax states (xor 16, then xor 32)
#pragma unroll
  for (int off = 16; off <= 32; off <<= 1) {
    float mo = __shfl_xor(m, off);
    float so = __shfl_xor(s, off);
    float ao[8];
#pragma unroll
    for (int j = 0; j < 8; ++j) ao[j] = __shfl_xor(acc[j], off);
    float M = fmaxf(m, mo);
    float e0 = __expf(m - M), e1 = __expf(mo - M);
    s = fmaf(s, e0, so * e1);
#pragma unroll
    for (int j = 0; j < 8; ++j) acc[j] = fmaf(acc[j], e0, ao[j] * e1);
    m = M;
  }

  const float inv = 1.f / s;
  const float4 bA = *(const float4*)(bias + f8);
  const float4 bB = *(const float4*)(bias + f8 + 4);
  const float bb[8] = {bA.x, bA.y, bA.z, bA.w, bB.x, bB.y, bB.z, bB.w};
  float o[8];
#pragma unroll
  for (int j = 0; j < 8; ++j) o[j] = fmaxf(fmaf(acc[j], inv, bb[j]), 0.f);

  if (LAST == 0) {
    if (g == 0) {
      union { uint4 u; __half2 h[4]; } pk;
#pragma unroll
      for (int j = 0; j < 4; ++j) pk.h[j] = __floats2half2_rn(o[2 * j], o[2 * j + 1]);
      *(uint4*)((__half*)outp + (size_t)nid * FDIM + f8) = pk.u;
    }
  } else {
    const float4 wA = *(const float4*)(Wf + f8);
    const float4 wB = *(const float4*)(Wf + f8 + 4);
    float y = fmaf(o[0], wA.x, fmaf(o[1], wA.y, fmaf(o[2], wA.z,
              fmaf(o[3], wA.w, fmaf(o[4], wB.x, fmaf(o[5], wB.y,
              fmaf(o[6], wB.z, o[7] * wB.w)))))));
    y += __shfl_xor(y, 1);
    y += __shfl_xor(y, 2);
    y += __shfl_xor(y, 4);
    y += __shfl_xor(y, 8);
    if (lane == 0) ((float*)outp)[nid] = y + bf[0];
  }
}

extern "C" void kernel_launch(void* const* d_in, const int* in_sizes, int n_in,
                              void* d_out, int out_size, void* d_ws, size_t ws_size,
                              hipStream_t stream) {
  const float* x = (const float*)d_in[0];
  const int* ei = (const int*)d_in[1];
  const int n = in_sizes[0] / FDIM;
  const int e_cnt = in_sizes[1] / 2;
  const int* srcI = ei;
  const int* dstI = ei + e_cnt;

  const float* Wl[3]  = {(const float*)d_in[2], (const float*)d_in[6], (const float*)d_in[10]};
  const float* Wr[3]  = {(const float*)d_in[3], (const float*)d_in[7], (const float*)d_in[11]};
  const float* att[3] = {(const float*)d_in[4], (const float*)d_in[8], (const float*)d_in[12]};
  const float* bs[3]  = {(const float*)d_in[5], (const float*)d_in[9], (const float*)d_in[13]};
  const float* Wf = (const float*)d_in[14];
  const float* bf = (const float*)d_in[15];

  __half* xlh  = (__half*)d_ws;
  __half* xrh  = xlh + (size_t)n * FDIM;
  __half* hbufh = xrh + (size_t)n * FDIM;
  int* deg    = (int*)(hbufh + (size_t)n * FDIM);
  int* rowptr = deg + n;
  int* rowcur = rowptr + n + 1;
  int* csr    = rowcur + n;
  int* btot   = csr + e_cnt;
  __half* Wt  = (__half*)(btot + 1024);   // 6 x 128 x 128 fp16 = 192 KiB

  const int nb = (n + 1023) / 1024;

  // ---- weight transpose/convert + CSR build (serve all 3 layers) ----
  prep_w<<<6, 256, 0, stream>>>(Wl[0], Wr[0], Wl[1], Wr[1], Wl[2], Wr[2], Wt);
  (void)hipMemsetAsync(deg, 0, (size_t)n * sizeof(int), stream);
  hist_dst<<<(e_cnt + 255) / 256, 256, 0, stream>>>(dstI, deg, e_cnt);
  scan_local<<<nb, 1024, 0, stream>>>(deg, rowptr, btot, n);
  scan_btot<<<1, 1024, 0, stream>>>(btot, nb);
  scan_add<<<nb, 1024, 0, stream>>>(rowptr, rowcur, btot, n, e_cnt);
  scatter_csr<<<(e_cnt + 255) / 256, 256, 0, stream>>>(srcI, dstI, rowcur, csr, e_cnt);

  const int gemmGrid = (n + 127) / 128;
  const int nodeBlocks = (n + 3) / 4;  // 4 waves (nodes) per block

  for (int L = 0; L < 3; ++L) {
    const __half* Wlt = Wt + (size_t)(2 * L) * FDIM * FDIM;
    const __half* Wrt = Wt + (size_t)(2 * L + 1) * FDIM * FDIM;
    if (L == 0)
      gemm_mfma<float><<<gemmGrid, 512, 0, stream>>>(x, Wlt, Wrt, xlh, xrh, n);
    else
      gemm_mfma<__half><<<gemmGrid, 512, 0, stream>>>(hbufh, Wlt, Wrt, xlh, xrh, n);
    if (L < 2) {
      fused_attn<0><<<nodeBlocks, 256, 0, stream>>>(xlh, xrh, rowptr, csr, att[L],
                                                    bs[L], nullptr, nullptr, hbufh, n);
    } else {
      fused_attn<1><<<nodeBlocks, 256, 0, stream>>>(xlh, xrh, rowptr, csr, att[L],
                                                    bs[L], Wf, bf, d_out, n);
    }
  }
}

// Round 11
// 367.725 us; speedup vs baseline: 1.0990x; 1.0990x over previous
//
#include <hip/hip_runtime.h>
#include <hip/hip_fp16.h>

// GATv2 x3 + FC on MI355X. N=50000, E=800000(+N self loops), F=128, H=4, C=32.
// R10: revert R9's attn 3-deep prefetch (issue-bound: VALUBusy fell 93->80)
//      and R9's single-stage gemm (1 block/CU occupancy) back to R8 forms.
//      NEW: dst-sliced hist/scatter — 8 block-groups (slice=bid&7 ~ XCD),
//      each reads all edges coalesced but only handles dst in its 1/8 range,
//      so csr/rowcur/deg lines are written from ONE XCD (WRITE was 52MB for
//      3.2MB payload = cross-XCD line bouncing).
constexpr int FDIM = 128;   // H*C
constexpr float SLOPE = 0.2f;

using half8 = __attribute__((ext_vector_type(8))) _Float16;
using f32x4 = __attribute__((ext_vector_type(4))) float;
using h2v   = __attribute__((ext_vector_type(2))) _Float16;

union H2U { __half2 s; h2v v; unsigned int u; };

__device__ __forceinline__ float fdot2f(h2v a, h2v b, float c) {
  return __builtin_amdgcn_fdot2(a, b, c, false);
}

union U4 { uint4 u; __half2 h[4]; };

// logit partial for 8 features held as 4 half2: sum att*lrelu(xa+xr)
__device__ __forceinline__ float edge_logit(const __half2* xa2, const __half2* xr2,
                                            const h2v* att2, h2v c02) {
  float p = 0.f;
#pragma unroll
  for (int j = 0; j < 4; ++j) {
    H2U ua, ur;
    ua.s = xa2[j]; ur.s = xr2[j];
    h2v z = ua.v + ur.v;                              // v_pk_add_f16
    h2v lr = __builtin_elementwise_max(z, z * c02);   // lrelu = max(x, 0.2x)
    p = fdot2f(lr, att2[j], p);
  }
  return p;
}

// ---- prep_w: W[k][c] fp32 -> Wt[c][k] fp16, 6 matrices (one per block) ---
__global__ __launch_bounds__(256) void prep_w(
    const float* __restrict__ W0, const float* __restrict__ W1,
    const float* __restrict__ W2, const float* __restrict__ W3,
    const float* __restrict__ W4, const float* __restrict__ W5,
    __half* __restrict__ Wt) {
  const float* Ws[6] = {W0, W1, W2, W3, W4, W5};
  const float* W = Ws[blockIdx.x];
  __half* o = Wt + (size_t)blockIdx.x * FDIM * FDIM;
  const int t = threadIdx.x;
  const int c4 = (t & 31) * 4;
#pragma unroll
  for (int rep = 0; rep < 16; ++rep) {
    int k = (t >> 5) + rep * 8;
    float4 v = *(const float4*)(W + (size_t)k * FDIM + c4);
    o[(size_t)(c4 + 0) * FDIM + k] = __float2half(v.x);
    o[(size_t)(c4 + 1) * FDIM + k] = __float2half(v.y);
    o[(size_t)(c4 + 2) * FDIM + k] = __float2half(v.z);
    o[(size_t)(c4 + 3) * FDIM + k] = __float2half(v.w);
  }
}

// ---- gemm_mfma (R8 form): xl = hin@Wl, xr = hin@Wr -----------------------
// 512 threads = 8 waves: wave w -> output sel=w>>2 (xl/xr), row-block w&3.
// BK=32 staged loop, [*][40] padded LDS, 4 blocks/CU.
template <typename TIN>
__global__ __launch_bounds__(512, 4) void gemm_mfma(
    const TIN* __restrict__ hin, const __half* __restrict__ Wlt,
    const __half* __restrict__ Wrt, __half* __restrict__ xl,
    __half* __restrict__ xr, int n) {
  __shared__ __half Ah[128][40];
  __shared__ __half Bsl[2][128][40];
  const int tid = threadIdx.x;
  const int row0 = blockIdx.x * 128;
  const int wv = tid >> 6;
  const int lane = tid & 63;
  const int sel = wv >> 2;       // 0: xl, 1: xr
  const int rb = wv & 3;         // 32-row block within tile
  const int l15 = lane & 15;
  const int l4 = lane >> 4;      // 0..3

  f32x4 acc[2][8];
#pragma unroll
  for (int i = 0; i < 2; ++i)
#pragma unroll
    for (int j = 0; j < 8; ++j) acc[i][j] = (f32x4){0.f, 0.f, 0.f, 0.f};

  const int sr = tid >> 2;            // A row 0..127
  const int sc = (tid & 3) * 8;       // A k-chunk 0/8/16/24
  const int bslab = tid >> 8;         // 0: Wl, 1: Wr
  const int bidx = tid & 255;
  const int bc = bidx >> 1;           // col 0..127
  const int bko = (bidx & 1) * 16;    // k offset 0/16
  const __half* Wsrc = bslab ? Wrt : Wlt;
  const int gr = row0 + sr;

  for (int k0 = 0; k0 < 128; k0 += 32) {
    if (k0) __syncthreads();
    {  // stage A rows row0+sr, k = k0+sc..+7 -> one 16B LDS write
      union { uint4 u; __half h[8]; } pk;
      if constexpr (sizeof(TIN) == 4) {
        float4 v0 = make_float4(0.f, 0.f, 0.f, 0.f), v1 = v0;
        if (gr < n) {
          v0 = *(const float4*)((const float*)hin + (size_t)gr * FDIM + k0 + sc);
          v1 = *(const float4*)((const float*)hin + (size_t)gr * FDIM + k0 + sc + 4);
        }
        pk.h[0] = __float2half(v0.x); pk.h[1] = __float2half(v0.y);
        pk.h[2] = __float2half(v0.z); pk.h[3] = __float2half(v0.w);
        pk.h[4] = __float2half(v1.x); pk.h[5] = __float2half(v1.y);
        pk.h[6] = __float2half(v1.z); pk.h[7] = __float2half(v1.w);
      } else {
        pk.u = make_uint4(0u, 0u, 0u, 0u);
        if (gr < n)
          pk.u = *(const uint4*)((const __half*)hin + (size_t)gr * FDIM + k0 + sc);
      }
      *(uint4*)&Ah[sr][sc] = pk.u;
    }
    {  // stage B slab: Wt[col][k0+bko .. +16] (already fp16)
      const uint4* src = (const uint4*)(Wsrc + (size_t)bc * FDIM + k0 + bko);
      uint4 w0 = src[0], w1 = src[1];
      *(uint4*)&Bsl[bslab][bc][bko] = w0;
      *(uint4*)&Bsl[bslab][bc][bko + 8] = w1;
    }
    __syncthreads();
    half8 a0 = *(const half8*)&Ah[rb * 32 + l15][l4 * 8];
    half8 a1 = *(const half8*)&Ah[rb * 32 + 16 + l15][l4 * 8];
#pragma unroll
    for (int nf = 0; nf < 8; ++nf) {
      half8 b = *(const half8*)&Bsl[sel][nf * 16 + l15][l4 * 8];
      acc[0][nf] = __builtin_amdgcn_mfma_f32_16x16x32_f16(a0, b, acc[0][nf], 0, 0, 0);
      acc[1][nf] = __builtin_amdgcn_mfma_f32_16x16x32_f16(a1, b, acc[1][nf], 0, 0, 0);
    }
  }

  __half* out = sel ? xr : xl;
#pragma unroll
  for (int af = 0; af < 2; ++af) {
#pragma unroll
    for (int nf = 0; nf < 8; ++nf) {
      int col = nf * 16 + l15;
#pragma unroll
      for (int r = 0; r < 4; ++r) {
        int row = row0 + rb * 32 + af * 16 + l4 * 4 + r;
        if (row < n) out[(size_t)row * FDIM + col] = __float2half(acc[af][nf][r]);
      }
    }
  }
}

// --------- CSR build: dst-sliced histogram -> scan -> dst-sliced scatter --
// slice = blockIdx.x & 7 (round-robin block->XCD): all writes to a given
// deg/rowcur/csr line come from one XCD -> no cross-XCD line bouncing.
__global__ __launch_bounds__(256) void hist_dst(const int* __restrict__ dstI,
                                                int* __restrict__ deg,
                                                int e_cnt, int n) {
  const int slice = blockIdx.x & 7;
  const int lo = (n * slice) >> 3;
  const int hi = (n * (slice + 1)) >> 3;
  int i = (blockIdx.x >> 3) * blockDim.x + threadIdx.x;
  const int stride = (gridDim.x >> 3) * blockDim.x;
  for (; i < e_cnt; i += stride) {
    int d = dstI[i];
    if (d >= lo && d < hi) atomicAdd(&deg[d], 1);
  }
}

__global__ __launch_bounds__(1024) void scan_local(
    const int* __restrict__ deg, int* __restrict__ rowptr,
    int* __restrict__ btot, int n) {
  __shared__ int lds[1024];
  const int t = threadIdx.x;
  const int i = blockIdx.x * 1024 + t;
  int v = (i < n) ? deg[i] : 0;
  lds[t] = v;
  __syncthreads();
  for (int off = 1; off < 1024; off <<= 1) {
    int u = (t >= off) ? lds[t - off] : 0;
    __syncthreads();
    lds[t] += u;
    __syncthreads();
  }
  if (i < n) rowptr[i] = lds[t] - v;  // exclusive within block
  if (t == 1023) btot[blockIdx.x] = lds[1023];
}

__global__ __launch_bounds__(1024) void scan_btot(int* __restrict__ btot, int nb) {
  __shared__ int lds[1024];
  const int t = threadIdx.x;
  int v = (t < nb) ? btot[t] : 0;
  lds[t] = v;
  __syncthreads();
  for (int off = 1; off < 1024; off <<= 1) {
    int u = (t >= off) ? lds[t - off] : 0;
    __syncthreads();
    lds[t] += u;
    __syncthreads();
  }
  if (t < nb) btot[t] = lds[t] - v;
}

__global__ __launch_bounds__(1024) void scan_add(
    int* __restrict__ rowptr, int* __restrict__ rowcur,
    const int* __restrict__ btot, int n, int e_cnt) {
  const int i = blockIdx.x * 1024 + threadIdx.x;
  if (i < n) {
    int v = rowptr[i] + btot[blockIdx.x];
    rowptr[i] = v;
    rowcur[i] = v;
  }
  if (i == 0) rowptr[n] = e_cnt;
}

__global__ __launch_bounds__(256) void scatter_csr(
    const int* __restrict__ srcI, const int* __restrict__ dstI,
    int* __restrict__ rowcur, int* __restrict__ csr, int e_cnt, int n) {
  const int slice = blockIdx.x & 7;
  const int lo = (n * slice) >> 3;
  const int hi = (n * (slice + 1)) >> 3;
  int i = (blockIdx.x >> 3) * blockDim.x + threadIdx.x;
  const int stride = (gridDim.x >> 3) * blockDim.x;
  for (; i < e_cnt; i += stride) {
    int d = dstI[i];
    int s = srcI[i];           // coalesced unconditional read
    if (d >= lo && d < hi) {
      int pos = atomicAdd(&rowcur[d], 1);
      csr[pos] = s;
    }
  }
}

// ------- fused per-node GATv2 (R8 form): 4 edges/wave, 2-deep prefetch ----
// lane = g*16 + q; group g handles edges rs+4t+g; lane q covers features
// q*8..q*8+7 (head = q>>2). Self-loop seeds group 0's state.
template <int LAST>
__global__ __launch_bounds__(256) void fused_attn(
    const __half* __restrict__ xl, const __half* __restrict__ xr,
    const int* __restrict__ rowptr, const int* __restrict__ csr,
    const float* __restrict__ att, const float* __restrict__ bias,
    const float* __restrict__ Wf, const float* __restrict__ bf,
    void* __restrict__ outp, int n) {
  const int nid = (int)((blockIdx.x * (size_t)blockDim.x + threadIdx.x) >> 6);
  const int lane = threadIdx.x & 63;
  if (nid >= n) return;
  const int g = lane >> 4;
  const int q = lane & 15;
  const int f8 = q * 8;
  const h2v c02 = {(_Float16)SLOPE, (_Float16)SLOPE};
  const float4 aA = *(const float4*)(att + f8);
  const float4 aB = *(const float4*)(att + f8 + 4);
  h2v att2[4] = {{(_Float16)aA.x, (_Float16)aA.y}, {(_Float16)aA.z, (_Float16)aA.w},
                 {(_Float16)aB.x, (_Float16)aB.y}, {(_Float16)aB.z, (_Float16)aB.w}};
  U4 xru, xlu;
  xru.u = *(const uint4*)(xr + (size_t)nid * FDIM + f8);
  xlu.u = *(const uint4*)(xl + (size_t)nid * FDIM + f8);

  // self-edge logit
  float ps = edge_logit(xlu.h, xru.h, att2, c02);
  ps += __shfl_xor(ps, 1);
  ps += __shfl_xor(ps, 2);

  float m = (g == 0) ? ps : -1e30f;
  float s = (g == 0) ? 1.f : 0.f;
  float acc[8];
#pragma unroll
  for (int j = 0; j < 4; ++j) {
    float2 f = __half22float2(xlu.h[j]);
    acc[2 * j] = (g == 0) ? f.x : 0.f;
    acc[2 * j + 1] = (g == 0) ? f.y : 0.f;
  }

  const int rs = rowptr[nid], re = rowptr[nid + 1];
  const int j0 = rs + g;
  bool v0 = j0 < re, v1 = (j0 + 4) < re;
  U4 cur, nx1;
  cur.u = make_uint4(0u, 0u, 0u, 0u);
  nx1.u = cur.u;
  if (v0) cur.u = *(const uint4*)(xl + (size_t)csr[j0] * FDIM + f8);
  if (v1) nx1.u = *(const uint4*)(xl + (size_t)csr[j0 + 4] * FDIM + f8);

  for (int t = rs; t < re; t += 4) {
    const int jn = t + 8 + g;
    const bool vn = jn < re;
    U4 nx2;
    nx2.u = make_uint4(0u, 0u, 0u, 0u);
    if (vn) nx2.u = *(const uint4*)(xl + (size_t)csr[jn] * FDIM + f8);

    float p = edge_logit(cur.h, xru.h, att2, c02);
    p += __shfl_xor(p, 1);
    p += __shfl_xor(p, 2);
    if (v0) {
      float mn = fmaxf(m, p);
      float sc = __expf(m - mn);
      float w = __expf(p - mn);
      s = fmaf(s, sc, w);
#pragma unroll
      for (int j = 0; j < 4; ++j) {  // fma_mix: (float)half fused by compiler
        acc[2 * j] = fmaf(acc[2 * j], sc, w * (float)__low2half(cur.h[j]));
        acc[2 * j + 1] = fmaf(acc[2 * j + 1], sc, w * (float)__high2half(cur.h[j]));
      }
      m = mn;
    }
    v0 = v1; v1 = vn; cur = nx1; nx1 = nx2;
  }

  // merge the 4 groups' online-softmax states (xor 16, then xor 32)
#pragma unroll
  for (int off = 16; off <= 32; off <<= 1) {
    float mo = __shfl_xor(m, off);
    float so = __shfl_xor(s, off);
    float ao[8];
#pragma unroll
    for (int j = 0; j < 8; ++j) ao[j] = __shfl_xor(acc[j], off);
    float M = fmaxf(m, mo);
    float e0 = __expf(m - M), e1 = __expf(mo - M);
    s = fmaf(s, e0, so * e1);
#pragma unroll
    for (int j = 0; j < 8; ++j) acc[j] = fmaf(acc[j], e0, ao[j] * e1);
    m = M;
  }

  const float inv = 1.f / s;
  const float4 bA = *(const float4*)(bias + f8);
  const float4 bB = *(const float4*)(bias + f8 + 4);
  const float bb[8] = {bA.x, bA.y, bA.z, bA.w, bB.x, bB.y, bB.z, bB.w};
  float o[8];
#pragma unroll
  for (int j = 0; j < 8; ++j) o[j] = fmaxf(fmaf(acc[j], inv, bb[j]), 0.f);

  if (LAST == 0) {
    if (g == 0) {
      union { uint4 u; __half2 h[4]; } pk;
#pragma unroll
      for (int j = 0; j < 4; ++j) pk.h[j] = __floats2half2_rn(o[2 * j], o[2 * j + 1]);
      *(uint4*)((__half*)outp + (size_t)nid * FDIM + f8) = pk.u;
    }
  } else {
    const float4 wA = *(const float4*)(Wf + f8);
    const float4 wB = *(const float4*)(Wf + f8 + 4);
    float y = fmaf(o[0], wA.x, fmaf(o[1], wA.y, fmaf(o[2], wA.z,
              fmaf(o[3], wA.w, fmaf(o[4], wB.x, fmaf(o[5], wB.y,
              fmaf(o[6], wB.z, o[7] * wB.w)))))));
    y += __shfl_xor(y, 1);
    y += __shfl_xor(y, 2);
    y += __shfl_xor(y, 4);
    y += __shfl_xor(y, 8);
    if (lane == 0) ((float*)outp)[nid] = y + bf[0];
  }
}

extern "C" void kernel_launch(void* const* d_in, const int* in_sizes, int n_in,
                              void* d_out, int out_size, void* d_ws, size_t ws_size,
                              hipStream_t stream) {
  const float* x = (const float*)d_in[0];
  const int* ei = (const int*)d_in[1];
  const int n = in_sizes[0] / FDIM;
  const int e_cnt = in_sizes[1] / 2;
  const int* srcI = ei;
  const int* dstI = ei + e_cnt;

  const float* Wl[3]  = {(const float*)d_in[2], (const float*)d_in[6], (const float*)d_in[10]};
  const float* Wr[3]  = {(const float*)d_in[3], (const float*)d_in[7], (const float*)d_in[11]};
  const float* att[3] = {(const float*)d_in[4], (const float*)d_in[8], (const float*)d_in[12]};
  const float* bs[3]  = {(const float*)d_in[5], (const float*)d_in[9], (const float*)d_in[13]};
  const float* Wf = (const float*)d_in[14];
  const float* bf = (const float*)d_in[15];

  __half* xlh  = (__half*)d_ws;
  __half* xrh  = xlh + (size_t)n * FDIM;
  __half* hbufh = xrh + (size_t)n * FDIM;
  int* deg    = (int*)(hbufh + (size_t)n * FDIM);
  int* rowptr = deg + n;
  int* rowcur = rowptr + n + 1;
  int* csr    = rowcur + n;
  int* btot   = csr + e_cnt;
  __half* Wt  = (__half*)(btot + 1024);   // 6 x 128 x 128 fp16 = 192 KiB

  const int nb = (n + 1023) / 1024;
  const int sliceBlocks = 8 * 256;   // 8 dst-slices x 256 blocks each

  // ---- weight transpose/convert + CSR build (serve all 3 layers) ----
  prep_w<<<6, 256, 0, stream>>>(Wl[0], Wr[0], Wl[1], Wr[1], Wl[2], Wr[2], Wt);
  (void)hipMemsetAsync(deg, 0, (size_t)n * sizeof(int), stream);
  hist_dst<<<sliceBlocks, 256, 0, stream>>>(dstI, deg, e_cnt, n);
  scan_local<<<nb, 1024, 0, stream>>>(deg, rowptr, btot, n);
  scan_btot<<<1, 1024, 0, stream>>>(btot, nb);
  scan_add<<<nb, 1024, 0, stream>>>(rowptr, rowcur, btot, n, e_cnt);
  scatter_csr<<<sliceBlocks, 256, 0, stream>>>(srcI, dstI, rowcur, csr, e_cnt, n);

  const int gemmGrid = (n + 127) / 128;
  const int nodeBlocks = (n + 3) / 4;  // 4 waves (nodes) per block

  for (int L = 0; L < 3; ++L) {
    const __half* Wlt = Wt + (size_t)(2 * L) * FDIM * FDIM;
    const __half* Wrt = Wt + (size_t)(2 * L + 1) * FDIM * FDIM;
    if (L == 0)
      gemm_mfma<float><<<gemmGrid, 512, 0, stream>>>(x, Wlt, Wrt, xlh, xrh, n);
    else
      gemm_mfma<__half><<<gemmGrid, 512, 0, stream>>>(hbufh, Wlt, Wrt, xlh, xrh, n);
    if (L < 2) {
      fused_attn<0><<<nodeBlocks, 256, 0, stream>>>(xlh, xrh, rowptr, csr, att[L],
                                                    bs[L], nullptr, nullptr, hbufh, n);
    } else {
      fused_attn<1><<<nodeBlocks, 256, 0, stream>>>(xlh, xrh, rowptr, csr, att[L],
                                                    bs[L], Wf, bf, d_out, n);
    }
  }
}